// Round 2
// baseline (450.311 us; speedup 1.0000x reference)
//
#include <hip/hip_runtime.h>
#include <math.h>

#define NB 16
#define DD 256       // D (in channels)
#define LL 16384     // H*W
#define DO 256       // D_OUT

// workspace float offsets
#define WS_QKP   0                    // 8*256 qk partials
#define WS_QW2P  2048                 // 8*256 qw2 partials
#define WS_W1T   4096                 // 65536  w1t[f][o]
#define WS_VWT   (WS_W1T + 65536)     // 65536  v_wt[d][o]
#define WS_PQ    (WS_VWT + 65536)     // 16384
#define WS_M     (WS_PQ + LL)         // 16*32
#define WS_DEN   (WS_M + NB*32)       // 16*32
#define WS_NUM   (WS_DEN + NB*32)     // 16*32*256
// total ~283648 floats (~1.08 MB) of d_ws

__device__ __forceinline__ float gelu_tanh(float u) {
    float u3 = u*u*u;
    return 0.5f*u*(1.0f + tanhf(0.7978845608028654f*(u + 0.044715f*u3)));
}

// ---- K0: grid 528.
// blocks 0..7   : qk partial over o-chunk     (k_w^T q)
// blocks 8..15  : qw2 partial over o-chunk    (w2^T q)
// blocks 16..271: w1t[f][o] = w1[o][f]
// blocks 272..527: v_wt[d][o] = v_w[o][d]
// NOTE: c1=k_b.q and c2=b2.q are constant over l,n -> softmax-invariant -> dropped.
__global__ __launch_bounds__(256) void k0(const float* __restrict__ query,
        const float* __restrict__ k_w, const float* __restrict__ w2,
        const float* __restrict__ w1, const float* __restrict__ v_w,
        float* __restrict__ ws) {
    int t = threadIdx.x, b = blockIdx.x;
    if (b < 16) {
        bool is_k = (b < 8);
        int c = b & 7;
        const float* M = is_k ? k_w : w2;
        float a = 0.f;
        #pragma unroll
        for (int oi = 0; oi < 32; ++oi) {
            int o = c*32 + oi;
            a += M[o*DD + t] * query[o];    // row coalesced, query[o] scalar-load
        }
        ws[(is_k ? WS_QKP : WS_QW2P) + c*256 + t] = a;
    } else if (b < 272) {
        int f = b - 16;
        ws[WS_W1T + f*DO + t] = w1[t*DO + f];
    } else {
        int d = b - 272;
        ws[WS_VWT + d*DO + t] = v_w[t*DD + d];
    }
}

// ---- K1: pq[l] = gelu(feats[l] @ w1^T + b1) . qw2.  grid 512, 32 l per block.
// featsT layout [256 f][36 pad] so the 8 per-wave feats values are one contiguous
// 32B chunk -> 2 broadcast ds_read_b128 instead of 8 scalar broadcasts per f.
__global__ __launch_bounds__(256) void k1_pq(const float* __restrict__ Wr,
        const float* __restrict__ b1, float* __restrict__ ws) {
    __shared__ __align__(16) float featsT[256*36];   // 36 KB
    __shared__ __align__(16) float wbuf[32*256];     // 32 KB
    int t = threadIdx.x;
    int w = t >> 6, lane = t & 63;
    int l0 = blockIdx.x * 32;
    int r = t & 127;
    float wr0 = Wr[r*2], wr1 = Wr[r*2+1];
    bool is_cos = (t < 128);          // wave-uniform branch
    #pragma unroll 8
    for (int lr = 0; lr < 32; ++lr) {
        int l = l0 + lr;
        int i = l >> 7, j = l & 127;
        float y = -1.0f + (2.0f/127.0f)*(float)i;
        float xg = -1.0f + (2.0f/127.0f)*(float)j;
        float p = y*wr0 + xg*wr1;
        featsT[t*36 + lr] = (is_cos ? cosf(p) : sinf(p)) * 0.0625f;  // /sqrt(256)
    }
    int o4 = lane * 4;                // each wave covers all 256 o; wave owns 8 l's
    float z[8][4];
    #pragma unroll
    for (int a = 0; a < 8; ++a) { z[a][0]=0.f; z[a][1]=0.f; z[a][2]=0.f; z[a][3]=0.f; }
    // qw2[o4..o4+3] = sum of 8 partials
    float4 qwv; qwv.x = 0.f; qwv.y = 0.f; qwv.z = 0.f; qwv.w = 0.f;
    #pragma unroll
    for (int c = 0; c < 8; ++c) {
        float4 p = *(const float4*)(ws + WS_QW2P + c*256 + o4);
        qwv.x += p.x; qwv.y += p.y; qwv.z += p.z; qwv.w += p.w;
    }
    for (int fc = 0; fc < 8; ++fc) {
        // stage w1t[fc*32 .. +31][:] into LDS (coalesced float4)
        #pragma unroll
        for (int i2 = 0; i2 < 8; ++i2) {
            int idx = i2*256 + t;
            int fl = idx >> 6;
            int c = (idx & 63) * 4;
            *(float4*)(wbuf + fl*256 + c) =
                *(const float4*)(ws + WS_W1T + (fc*32+fl)*DO + c);
        }
        __syncthreads();              // stage done (covers featsT on first iter)
        for (int fl = 0; fl < 32; ++fl) {
            float4 wv = *(const float4*)(wbuf + fl*256 + o4);   // conflict-free b128
            const float* fr = featsT + (fc*32+fl)*36 + w*8;     // 16B-aligned
            float4 fa = *(const float4*)(fr);                   // broadcast b128
            float4 fb = *(const float4*)(fr+4);                 // broadcast b128
            float fv[8] = {fa.x,fa.y,fa.z,fa.w,fb.x,fb.y,fb.z,fb.w};
            #pragma unroll
            for (int lr = 0; lr < 8; ++lr) {
                z[lr][0] += fv[lr]*wv.x; z[lr][1] += fv[lr]*wv.y;
                z[lr][2] += fv[lr]*wv.z; z[lr][3] += fv[lr]*wv.w;
            }
        }
        __syncthreads();
    }
    float4 b1v = *(const float4*)(b1 + o4);
    #pragma unroll
    for (int lr = 0; lr < 8; ++lr) {
        float pp = gelu_tanh(z[lr][0]+b1v.x)*qwv.x + gelu_tanh(z[lr][1]+b1v.y)*qwv.y
                 + gelu_tanh(z[lr][2]+b1v.z)*qwv.z + gelu_tanh(z[lr][3]+b1v.w)*qwv.w;
        for (int off = 32; off > 0; off >>= 1) pp += __shfl_xor(pp, off);
        if (lane == 0) ws[WS_PQ + l0 + w*8 + lr] = pp;
    }
}

// ---- K2: single pass over x, fully register-resident (no LDS tile).
// grid 512 = (n=bid>>5, lb=bid&31), 512 l per block, 8 tiles of 64 l.
// Thread t owns d = {16*i2 + (t>>4)} x l = {l0 + (t&15)*4 .. +3} in regs.
// Scores: per-thread FMA + shfl_xor(16,32) + part[256] combine.
// Num: per-thread numacc[16], shfl_xor(1,2,4,8) at end. 2 barriers/tile.
__global__ __launch_bounds__(256) void k2_main(const float* __restrict__ x,
        float* __restrict__ ws) {
    __shared__ float qk_s[DD];
    __shared__ __align__(16) float e_s[64];
    __shared__ __align__(16) float part[256];
    __shared__ float m_s, den_s, sc_s;
    int t = threadIdx.x;
    int n = blockIdx.x >> 5, lb = blockIdx.x & 31;
    const float* xb = x + (size_t)n * DD * LL + lb * 512;
    int dld = t >> 4, li = (t & 15) * 4;
    int w = t >> 6, lane = t & 63;
    // issue tile-0 loads first so HBM starts immediately
    float4 v[2][16];
    #pragma unroll
    for (int i2 = 0; i2 < 16; ++i2)
        v[0][i2] = *(const float4*)(xb + (size_t)(i2*16 + dld)*LL + li);
    float aqk = 0.f;
    #pragma unroll
    for (int c = 0; c < 8; ++c) aqk += ws[WS_QKP + c*256 + t];
    qk_s[t] = aqk;
    if (t == 0) { m_s = -INFINITY; den_s = 0.f; sc_s = 0.f; }
    float pqv[8];
    if (t < 64) {
        #pragma unroll
        for (int tb = 0; tb < 8; ++tb) pqv[tb] = ws[WS_PQ + lb*512 + tb*64 + t];
    }
    __syncthreads();
    float qkr[16];
    #pragma unroll
    for (int i2 = 0; i2 < 16; ++i2) qkr[i2] = qk_s[i2*16 + dld];
    float numacc[16];
    #pragma unroll
    for (int i2 = 0; i2 < 16; ++i2) numacc[i2] = 0.f;
    #pragma unroll
    for (int tb = 0; tb < 8; ++tb) {
        const int cur = tb & 1, nxt = cur ^ 1;
        if (tb < 7) {                 // prefetch next tile into the other buffer
            #pragma unroll
            for (int i2 = 0; i2 < 16; ++i2)
                v[nxt][i2] = *(const float4*)(xb + (size_t)(i2*16 + dld)*LL
                                              + (tb+1)*64 + li);
        }
        // score partials over this thread's 16 d's, for its 4 l's
        float sp0=0.f, sp1=0.f, sp2=0.f, sp3=0.f;
        #pragma unroll
        for (int i2 = 0; i2 < 16; ++i2) {
            sp0 += v[cur][i2].x * qkr[i2];
            sp1 += v[cur][i2].y * qkr[i2];
            sp2 += v[cur][i2].z * qkr[i2];
            sp3 += v[cur][i2].w * qkr[i2];
        }
        // sum the 4 dld-groups inside the wave (lanes c, c+16, c+32, c+48)
        sp0 += __shfl_xor(sp0, 16); sp0 += __shfl_xor(sp0, 32);
        sp1 += __shfl_xor(sp1, 16); sp1 += __shfl_xor(sp1, 32);
        sp2 += __shfl_xor(sp2, 16); sp2 += __shfl_xor(sp2, 32);
        sp3 += __shfl_xor(sp3, 16); sp3 += __shfl_xor(sp3, 32);
        if (lane < 16) {
            float4 spv; spv.x=sp0; spv.y=sp1; spv.z=sp2; spv.w=sp3;
            *(float4*)(part + w*64 + li) = spv;   // wave w partial over 64 d's
        }
        __syncthreads();
        if (t < 64) {   // wave 0 finalizes scores for this tile
            float dot = part[t] + part[64+t] + part[128+t] + part[192+t];
            float score = (dot + pqv[tb]) * 0.0625f;
            float mc = score;
            for (int off=32; off>0; off>>=1) mc = fmaxf(mc, __shfl_xor(mc, off));
            float mold = m_s;
            float mnew = fmaxf(mold, mc);
            float e = expf(score - mnew);
            e_s[t] = e;
            float dc = e;
            for (int off=32; off>0; off>>=1) dc += __shfl_xor(dc, off);
            if (t == 0) {
                float sc = expf(mold - mnew);   // first tile: exp(-inf)=0
                den_s = den_s*sc + dc;
                m_s = mnew;
                sc_s = sc;
            }
        }
        __syncthreads();
        float sc = sc_s;
        float4 e4 = *(const float4*)(e_s + li);   // this thread's 4 l-weights
        #pragma unroll
        for (int i2 = 0; i2 < 16; ++i2) {
            numacc[i2] = numacc[i2]*sc
                + e4.x*v[cur][i2].x + e4.y*v[cur][i2].y
                + e4.z*v[cur][i2].z + e4.w*v[cur][i2].w;
        }
    }
    // reduce numacc over the 16 lanes sharing a d-set (lane bits 0..3)
    #pragma unroll
    for (int i2 = 0; i2 < 16; ++i2) {
        float nv = numacc[i2];
        nv += __shfl_xor(nv, 1); nv += __shfl_xor(nv, 2);
        nv += __shfl_xor(nv, 4); nv += __shfl_xor(nv, 8);
        numacc[i2] = nv;
    }
    int pb = n*32 + lb;
    if ((t & 15) == 0) {              // lanes t=0,16,..,240: d = i2*16 + t/16
        #pragma unroll
        for (int i2 = 0; i2 < 16; ++i2)
            ws[WS_NUM + pb*256 + i2*16 + dld] = numacc[i2];
    }
    if (t == 0) { ws[WS_M + pb] = m_s; ws[WS_DEN + pb] = den_s; }
}

// ---- K3: combine partials per n, then out[n,o] = v_w[o,:].s + v_b[o].
// grid 64: block = (n = b>>2, o-quarter = b&3); waves split the d-sum.
__global__ __launch_bounds__(256) void k3_final(const float* __restrict__ ws,
        const float* __restrict__ v_b, float* __restrict__ out) {
    __shared__ float s_s[DD];
    __shared__ float part[256];
    int t = threadIdx.x;
    int n = blockIdx.x >> 2, oq = blockIdx.x & 3;
    float m = -INFINITY;
    #pragma unroll
    for (int lb = 0; lb < 32; ++lb) m = fmaxf(m, ws[WS_M + n*32 + lb]);
    float den = 0.f, sacc = 0.f;
    #pragma unroll 4
    for (int lb = 0; lb < 32; ++lb) {
        float sc = expf(ws[WS_M + n*32 + lb] - m);
        den += ws[WS_DEN + n*32 + lb] * sc;
        sacc += ws[WS_NUM + (n*32+lb)*256 + t] * sc;   // coalesced
    }
    s_s[t] = sacc / den;
    __syncthreads();
    int w = t >> 6, lane = t & 63;
    int o = oq*64 + lane;
    float acc = 0.f;
    #pragma unroll 8
    for (int i = 0; i < 64; ++i) {
        int d = w*64 + i;
        acc += ws[WS_VWT + d*DO + o] * s_s[d];         // coalesced, s broadcast
    }
    part[t] = acc;
    __syncthreads();
    if (t < 64)
        out[n*DO + oq*64 + t] = v_b[oq*64 + t]
            + part[t] + part[64+t] + part[128+t] + part[192+t];
}

extern "C" void kernel_launch(void* const* d_in, const int* in_sizes, int n_in,
                              void* d_out, int out_size, void* d_ws, size_t ws_size,
                              hipStream_t stream) {
    const float* x     = (const float*)d_in[0];
    const float* query = (const float*)d_in[1];
    const float* k_w   = (const float*)d_in[2];
    const float* v_w   = (const float*)d_in[4];
    const float* v_b   = (const float*)d_in[5];
    const float* Wr    = (const float*)d_in[6];
    const float* w1    = (const float*)d_in[7];
    const float* b1    = (const float*)d_in[8];
    const float* w2    = (const float*)d_in[9];
    float* ws  = (float*)d_ws;
    float* out = (float*)d_out;

    k0<<<528, 256, 0, stream>>>(query, k_w, w2, w1, v_w, ws);
    k1_pq<<<512, 256, 0, stream>>>(Wr, b1, ws);
    k2_main<<<512, 256, 0, stream>>>(x, ws);
    k3_final<<<64, 256, 0, stream>>>(ws, v_b, out);
}

// Round 3
// 434.432 us; speedup vs baseline: 1.0365x; 1.0365x over previous
//
#include <hip/hip_runtime.h>
#include <math.h>

#define NB 16
#define DD 256       // D (in channels)
#define LL 16384     // H*W
#define DO 256       // D_OUT

// workspace float offsets
#define WS_QKP   0                    // 8*256 qk partials
#define WS_QW2P  2048                 // 8*256 qw2 partials
#define WS_W1T   4096                 // 65536  w1t[f][o]
#define WS_VWT   (WS_W1T + 65536)     // 65536  v_wt[d][o]
#define WS_M     (WS_VWT + 65536)     // 16*512
#define WS_DEN   (WS_M + NB*512)      // 16*512
#define WS_NUM   (WS_DEN + NB*512)    // 16*512*256 = 2097152
// total ~2.25M floats (~9 MB) of d_ws

__device__ __forceinline__ float gelu_tanh(float u) {
    float u3 = u*u*u;
    return 0.5f*u*(1.0f + tanhf(0.7978845608028654f*(u + 0.044715f*u3)));
}

// LDS-only barrier: NO vmcnt drain (keeps global prefetch loads in flight).
// Producer-safe: own ds_writes retired (lgkmcnt 0) before s_barrier.
#define LGKMBAR() do {                                          \
    asm volatile("s_waitcnt lgkmcnt(0)" ::: "memory");          \
    __builtin_amdgcn_s_barrier();                               \
    asm volatile("" ::: "memory");                              \
} while (0)

// ---- K0: grid 528.
// blocks 0..7   : qk partial over o-chunk   (k_w^T q)
// blocks 8..15  : qw2 partial over o-chunk  (w2^T q)
// blocks 16..271: w1t[f][o] = w1[o][f]
// blocks 272..527: v_wt[d][o] = v_w[o][d]
// c1=k_b.q, c2=b2.q are constant over l,n -> softmax-invariant -> dropped.
__global__ __launch_bounds__(256) void k0(const float* __restrict__ query,
        const float* __restrict__ k_w, const float* __restrict__ w2,
        const float* __restrict__ w1, const float* __restrict__ v_w,
        float* __restrict__ ws) {
    int t = threadIdx.x, b = blockIdx.x;
    if (b < 16) {
        bool is_k = (b < 8);
        int c = b & 7;
        const float* M = is_k ? k_w : w2;
        float a = 0.f;
        #pragma unroll
        for (int oi = 0; oi < 32; ++oi) {
            int o = c*32 + oi;
            a += M[o*DD + t] * query[o];    // row coalesced, query[o] scalar
        }
        ws[(is_k ? WS_QKP : WS_QW2P) + c*256 + t] = a;
    } else if (b < 272) {
        int f = b - 16;
        ws[WS_W1T + f*DO + t] = w1[t*DO + f];
    } else {
        int d = b - 272;
        ws[WS_VWT + d*DO + t] = v_w[t*DD + d];
    }
}

// ---- K2 fused: grid 512 (lb), 256 threads. Block owns l = lb*32 .. +32,
// loops over all 16 n. Prologue computes pq for its 32 l (MLP, w1t from L2).
// Single-shot softmax per (n,lb): m, den, num partials -> ws. All barriers
// are lgkm-only so x prefetch loads survive them (continuous HBM stream).
__global__ __launch_bounds__(256) void k2_fused(const float* __restrict__ x,
        const float* __restrict__ Wr, const float* __restrict__ b1,
        float* __restrict__ ws) {
    __shared__ __align__(16) float featsT[256*36];   // 36 KB: [f][32 l pad 36]
    __shared__ float qk_s[DD];
    __shared__ float pq_s[32];
    __shared__ __align__(16) float part[128];
    __shared__ __align__(16) float e_s[32];
    int t = threadIdx.x;
    int lb = blockIdx.x;
    int l0 = lb * 32;
    int w = t >> 6, lane = t & 63;
    int dld = t >> 3, li4 = (t & 7) * 4;   // thread owns d=i2*32+dld, l=l0+li4..+3
    const float* xb = x + l0 + li4;

    // issue x prefetch for n=0,1 immediately (flows under the prologue)
    float4 vb[2][8];
    #pragma unroll
    for (int i2 = 0; i2 < 8; ++i2)
        vb[0][i2] = *(const float4*)(xb + ((size_t)(0*DD + i2*32 + dld))*LL);
    #pragma unroll
    for (int i2 = 0; i2 < 8; ++i2)
        vb[1][i2] = *(const float4*)(xb + ((size_t)(1*DD + i2*32 + dld))*LL);

    // qk_s[t] = sum of 8 partials
    float aqk = 0.f;
    #pragma unroll
    for (int c = 0; c < 8; ++c) aqk += ws[WS_QKP + c*256 + t];
    qk_s[t] = aqk;

    // featsT[f][lr]: f = t, lr = 0..31 (cos for t<128, sin else)
    {
        int r = t & 127;
        float wr0 = Wr[r*2], wr1 = Wr[r*2+1];
        bool is_cos = (t < 128);
        #pragma unroll 8
        for (int lr = 0; lr < 32; ++lr) {
            int l = l0 + lr;
            int i = l >> 7, j = l & 127;
            float y = -1.0f + (2.0f/127.0f)*(float)i;
            float xg = -1.0f + (2.0f/127.0f)*(float)j;
            float p = y*wr0 + xg*wr1;
            featsT[t*36 + lr] = (is_cos ? cosf(p) : sinf(p)) * 0.0625f;
        }
    }
    LGKMBAR();                         // featsT + qk_s visible

    // ---- MLP prologue: wave w owns l = l0 + w*8 .. +8; lane owns o4 = lane*4.
    // wv streamed from ws[W1T] (L2-resident, identical across waves -> L1 hits).
    float z[8][4];
    #pragma unroll
    for (int a = 0; a < 8; ++a) { z[a][0]=0.f; z[a][1]=0.f; z[a][2]=0.f; z[a][3]=0.f; }
    int o4 = lane * 4;
    const float* w1p = ws + WS_W1T + o4;
    const float* frp = featsT + w*8;
    #pragma unroll 4
    for (int f = 0; f < 256; ++f) {
        float4 wv = *(const float4*)(w1p + f*256);       // global b128, L1/L2
        float4 fa = *(const float4*)(frp + f*36);        // LDS broadcast b128
        float4 fbq = *(const float4*)(frp + f*36 + 4);   // LDS broadcast b128
        float fv[8] = {fa.x,fa.y,fa.z,fa.w,fbq.x,fbq.y,fbq.z,fbq.w};
        #pragma unroll
        for (int lr = 0; lr < 8; ++lr) {
            z[lr][0] += fv[lr]*wv.x; z[lr][1] += fv[lr]*wv.y;
            z[lr][2] += fv[lr]*wv.z; z[lr][3] += fv[lr]*wv.w;
        }
    }
    {
        float4 qwv; qwv.x=0.f; qwv.y=0.f; qwv.z=0.f; qwv.w=0.f;
        #pragma unroll
        for (int c = 0; c < 8; ++c) {
            float4 p = *(const float4*)(ws + WS_QW2P + c*256 + o4);
            qwv.x += p.x; qwv.y += p.y; qwv.z += p.z; qwv.w += p.w;
        }
        float4 b1v = *(const float4*)(b1 + o4);
        #pragma unroll
        for (int lr = 0; lr < 8; ++lr) {
            float pp = gelu_tanh(z[lr][0]+b1v.x)*qwv.x + gelu_tanh(z[lr][1]+b1v.y)*qwv.y
                     + gelu_tanh(z[lr][2]+b1v.z)*qwv.z + gelu_tanh(z[lr][3]+b1v.w)*qwv.w;
            #pragma unroll
            for (int off = 32; off > 0; off >>= 1) pp += __shfl_xor(pp, off);
            if (lane == 0) pq_s[w*8 + lr] = pp;
        }
    }
    LGKMBAR();                         // pq_s visible

    float qkr[8];
    #pragma unroll
    for (int i2 = 0; i2 < 8; ++i2) qkr[i2] = qk_s[i2*32 + dld];

    // ---- main loop over n (fully unrolled: all vb indices static)
    #pragma unroll
    for (int n = 0; n < 16; ++n) {
        const float4 (&vc)[8] = vb[n & 1];
        // score partials: this thread's 32 d x its 4 l
        float sp0=0.f, sp1=0.f, sp2=0.f, sp3=0.f;
        #pragma unroll
        for (int i2 = 0; i2 < 8; ++i2) {
            sp0 += vc[i2].x * qkr[i2];
            sp1 += vc[i2].y * qkr[i2];
            sp2 += vc[i2].z * qkr[i2];
            sp3 += vc[i2].w * qkr[i2];
        }
        // reduce over the 8 dld-groups in this wave (lane bits 3,4,5)
        sp0 += __shfl_xor(sp0, 8); sp0 += __shfl_xor(sp0, 16); sp0 += __shfl_xor(sp0, 32);
        sp1 += __shfl_xor(sp1, 8); sp1 += __shfl_xor(sp1, 16); sp1 += __shfl_xor(sp1, 32);
        sp2 += __shfl_xor(sp2, 8); sp2 += __shfl_xor(sp2, 16); sp2 += __shfl_xor(sp2, 32);
        sp3 += __shfl_xor(sp3, 8); sp3 += __shfl_xor(sp3, 16); sp3 += __shfl_xor(sp3, 32);
        if (lane < 8) {
            float4 s4; s4.x=sp0; s4.y=sp1; s4.z=sp2; s4.w=sp3;
            *(float4*)(part + w*32 + li4) = s4;   // wave partial over its 64 d
        }
        LGKMBAR();
        if (t < 32) {                  // single-shot softmax for 32 scores
            float dot = part[t] + part[32+t] + part[64+t] + part[96+t];
            float score = (dot + pq_s[t]) * 0.0625f;
            float mc = score;
            #pragma unroll
            for (int off = 16; off > 0; off >>= 1) mc = fmaxf(mc, __shfl_xor(mc, off));
            float e = expf(score - mc);
            e_s[t] = e;
            float dc = e;
            #pragma unroll
            for (int off = 16; off > 0; off >>= 1) dc += __shfl_xor(dc, off);
            if (t == 0) {
                ws[WS_M + n*512 + lb] = mc;
                ws[WS_DEN + n*512 + lb] = dc;
            }
        }
        LGKMBAR();
        float4 e4 = *(const float4*)(e_s + li4);
        float na[8];
        #pragma unroll
        for (int i2 = 0; i2 < 8; ++i2)
            na[i2] = e4.x*vc[i2].x + e4.y*vc[i2].y + e4.z*vc[i2].z + e4.w*vc[i2].w;
        // reduce over the 8 lanes sharing a d (lane bits 0..2)
        #pragma unroll
        for (int i2 = 0; i2 < 8; ++i2) {
            na[i2] += __shfl_xor(na[i2], 1);
            na[i2] += __shfl_xor(na[i2], 2);
            na[i2] += __shfl_xor(na[i2], 4);
        }
        if ((t & 7) == 0) {
            #pragma unroll
            for (int i2 = 0; i2 < 8; ++i2)
                ws[WS_NUM + ((size_t)n*512 + lb)*256 + i2*32 + dld] = na[i2];
        }
        if (n + 2 < 16) {              // refill the buffer just consumed
            #pragma unroll
            for (int i2 = 0; i2 < 8; ++i2)
                vb[n & 1][i2] = *(const float4*)(xb
                    + ((size_t)((n+2)*DD + i2*32 + dld))*LL);
        }
    }
}

// ---- K3: combine 512 partials per n, then out[n,o] = v_wt.s + v_b.
// grid 64: (n = b>>2, oq = b&3). Waves split lb; float4 over d.
__global__ __launch_bounds__(256) void k3_final(const float* __restrict__ ws,
        const float* __restrict__ v_b, float* __restrict__ out) {
    __shared__ float red[256];
    __shared__ float e_sc[512];
    __shared__ float s_s[DD];
    __shared__ __align__(16) float sp[4*256];
    int t = threadIdx.x, n = blockIdx.x >> 2, oq = blockIdx.x & 3;
    const float* Mp = ws + WS_M + n*512;
    const float* Dp = ws + WS_DEN + n*512;
    float m0 = Mp[t], m1 = Mp[t+256];
    red[t] = fmaxf(m0, m1);
    __syncthreads();
    for (int s = 128; s > 0; s >>= 1) {
        if (t < s) red[t] = fmaxf(red[t], red[t+s]);
        __syncthreads();
    }
    float m = red[0];
    __syncthreads();                   // everyone got m before red reuse
    float e0 = expf(m0 - m), e1 = expf(m1 - m);
    e_sc[t] = e0; e_sc[t+256] = e1;
    red[t] = Dp[t]*e0 + Dp[t+256]*e1;
    __syncthreads();
    for (int s = 128; s > 0; s >>= 1) {
        if (t < s) red[t] += red[t+s];
        __syncthreads();
    }
    float den = red[0];
    __syncthreads();
    // s partials: wave w sums lb = w*128..+128; lane owns d = lane*4..+3
    int w = t >> 6, lane = t & 63;
    const float* NBp = ws + WS_NUM + (size_t)n*512*256;
    float ax=0.f, ay=0.f, az=0.f, aw=0.f;
    #pragma unroll 4
    for (int i = 0; i < 128; ++i) {
        int lbq = w*128 + i;
        float sc = e_sc[lbq];
        float4 v4 = *(const float4*)(NBp + (size_t)lbq*256 + lane*4);
        ax += sc*v4.x; ay += sc*v4.y; az += sc*v4.z; aw += sc*v4.w;
    }
    { float4 a4; a4.x=ax; a4.y=ay; a4.z=az; a4.w=aw;
      *(float4*)(sp + w*256 + lane*4) = a4; }
    __syncthreads();
    s_s[t] = (sp[t] + sp[256+t] + sp[512+t] + sp[768+t]) / den;
    __syncthreads();
    // out: wave w sums d = w*64..+64 for o = oq*64 + lane
    int o = oq*64 + lane;
    float acc = 0.f;
    #pragma unroll 8
    for (int i = 0; i < 64; ++i) {
        int d = w*64 + i;
        acc += ws[WS_VWT + d*DO + o] * s_s[d];   // coalesced, s broadcast
    }
    red[t] = acc;
    __syncthreads();
    if (t < 64)
        out[n*DO + oq*64 + t] = v_b[oq*64 + t]
            + red[t] + red[64+t] + red[128+t] + red[192+t];
}

extern "C" void kernel_launch(void* const* d_in, const int* in_sizes, int n_in,
                              void* d_out, int out_size, void* d_ws, size_t ws_size,
                              hipStream_t stream) {
    const float* x     = (const float*)d_in[0];
    const float* query = (const float*)d_in[1];
    const float* k_w   = (const float*)d_in[2];
    const float* v_w   = (const float*)d_in[4];
    const float* v_b   = (const float*)d_in[5];
    const float* Wr    = (const float*)d_in[6];
    const float* w1    = (const float*)d_in[7];
    const float* b1    = (const float*)d_in[8];
    const float* w2    = (const float*)d_in[9];
    float* ws  = (float*)d_ws;
    float* out = (float*)d_out;

    k0<<<528, 256, 0, stream>>>(query, k_w, w2, w1, v_w, ws);
    k2_fused<<<512, 256, 0, stream>>>(x, Wr, b1, ws);
    k3_final<<<64, 256, 0, stream>>>(ws, v_b, out);
}